// Round 7
// baseline (3750.869 us; speedup 1.0000x reference)
//
#include <hip/hip_runtime.h>
#include <hip/hip_bf16.h>
#include <math.h>

// ---------------- problem constants ----------------
#define BATCH 32
#define NTOK  197
#define NPATCH 196
#define DMODEL 768
#define NLAYER 12
#define NHEAD 12
#define HDIM  64
#define ROWS  (BATCH*NTOK)     // 6304
#define CROWS (BATCH*NPATCH)   // 6272
#define DFF   3072
#define DQKV  2304
#define DOUT  512
#define NBH   (BATCH*NHEAD)

// per-layer weight slab offsets (bf16 elems)
#define WOFF_IN   ((size_t)0)
#define WOFF_OUT  ((size_t)(DQKV*DMODEL))
#define WOFF_FC   (WOFF_OUT + (size_t)(DMODEL*DMODEL))
#define WOFF_CP   (WOFF_FC + (size_t)(DFF*DMODEL))
#define WTOT      (WOFF_CP + (size_t)(DMODEL*DFF))

// workspace layout (float units)
#define WS_H    ((size_t)0)
#define WS_QKVB (WS_H + (size_t)ROWS*DMODEL)
#define WS_GB   (WS_QKVB + (size_t)ROWS*DQKV/2)
#define WS_TB   (WS_GB + (size_t)ROWS*DFF/2)
#define WS_WL   (WS_TB + (size_t)ROWS*DMODEL/2)
#define WS_PTS  (WS_WL + WTOT/2)
#define WS_ADD  (WS_PTS + (size_t)DOUT*DMODEL/2)

typedef unsigned short ushort_t;
typedef __attribute__((ext_vector_type(8))) short bf16x8;
typedef __attribute__((ext_vector_type(4))) float f32x4;

__device__ inline ushort_t bf16rn(float x) {
    uint32_t u = __builtin_bit_cast(uint32_t, x);
    uint32_t r = (u + 0x7FFFu + ((u >> 16) & 1u)) >> 16;
    return (ushort_t)r;
}

#define GLL(src, dst) __builtin_amdgcn_global_load_lds( \
    (const __attribute__((address_space(1))) void*)(src), \
    (__attribute__((address_space(3))) void*)(dst), 16, 0, 0)

// ---------------- small kernels ----------------

__global__ void im2col_bf16_k(const float* __restrict__ x, ushort_t* __restrict__ out) {
    int idx = blockIdx.x * 256 + threadIdx.x;
    if (idx >= CROWS * DMODEL / 4) return;
    int r  = idx / (DMODEL / 4);
    int k4 = (idx - r * (DMODEL / 4)) * 4;
    int b = r / NPATCH, p = r - b * NPATCH;
    int py = p / 14, px = p - py * 14;
    int c = k4 >> 8, rem = k4 & 255, i = rem >> 4, j = rem & 15;
    const float* xp = x + (((size_t)(b * 3 + c) * 224) + py * 16 + i) * 224 + px * 16 + j;
    float4 v = *(const float4*)xp;
    ushort4 hv = {bf16rn(v.x), bf16rn(v.y), bf16rn(v.z), bf16rn(v.w)};
    *(ushort4*)(out + (size_t)r * DMODEL + k4) = hv;
}

__global__ void cvt_w_k(const float* __restrict__ W, ushort_t* __restrict__ out, int NK) {
    int idx = (blockIdx.x * 256 + threadIdx.x) * 4;
    if (idx >= NK) return;
    float4 v = *(const float4*)(W + idx);
    ushort4 hv = {bf16rn(v.x), bf16rn(v.y), bf16rn(v.z), bf16rn(v.w)};
    *(ushort4*)(out + idx) = hv;
}

__global__ void cvt_layer_k(const float* __restrict__ inW, const float* __restrict__ outW,
                            const float* __restrict__ fcW, const float* __restrict__ cpW,
                            ushort_t* __restrict__ wl) {
    size_t idx = ((size_t)blockIdx.x * 256 + threadIdx.x) * 4;
    if (idx >= WTOT) return;
    const float* src; size_t off;
    if (idx < WOFF_OUT)      { src = inW;  off = idx; }
    else if (idx < WOFF_FC)  { src = outW; off = idx - WOFF_OUT; }
    else if (idx < WOFF_CP)  { src = fcW;  off = idx - WOFF_FC; }
    else                     { src = cpW;  off = idx - WOFF_CP; }
    float4 v = *(const float4*)(src + off);
    ushort4 hv = {bf16rn(v.x), bf16rn(v.y), bf16rn(v.z), bf16rn(v.w)};
    *(ushort4*)(wl + idx) = hv;
}

__global__ void cvt_pT_k(const float* __restrict__ proj, ushort_t* __restrict__ out) {
    int idx = blockIdx.x * 256 + threadIdx.x;
    if (idx >= DOUT * DMODEL) return;
    int n = idx / DMODEL, k = idx - n * DMODEL;
    out[(size_t)n * DMODEL + k] = bf16rn(proj[(size_t)k * DOUT + n]);
}

__global__ void embed_k(const float* __restrict__ conv, const float* __restrict__ cls,
                        const float* __restrict__ pos, float* __restrict__ h) {
    int idx = blockIdx.x * 256 + threadIdx.x;
    if (idx >= ROWS * DMODEL) return;
    int r = idx / DMODEL, d = idx - r * DMODEL;
    int b = r / NTOK, tok = r - b * NTOK;
    float v = (tok == 0) ? cls[d] : conv[((size_t)(b * NPATCH + tok - 1)) * DMODEL + d];
    h[idx] = v + pos[(size_t)tok * DMODEL + d];
}

__global__ void gauss_k(float* __restrict__ add) {
    int idx = blockIdx.x * 256 + threadIdx.x;
    if (idx >= NTOK * NTOK) return;
    int i = idx / NTOK, j = idx - i * NTOK;
    float v = 0.f;
    if (i > 0 && j > 0) {
        int p = i - 1, q = j - 1;
        int di = q / 14 - p / 14;
        int dj = q % 14 - p % 14;
        v = expf(-(float)(di * di + dj * dj) * 0.02f);
    }
    add[idx] = v;
}

__global__ __launch_bounds__(256) void ln768_k(const float* __restrict__ in, float* __restrict__ out,
                                               const float* __restrict__ w, const float* __restrict__ b) {
    int row = blockIdx.x, tid = threadIdx.x;
    const float* x = in + (size_t)row * DMODEL;
    float v0 = x[tid], v1 = x[tid + 256], v2 = x[tid + 512];
    float s = v0 + v1 + v2;
    float s2 = v0 * v0 + v1 * v1 + v2 * v2;
    for (int o = 32; o > 0; o >>= 1) { s += __shfl_down(s, o); s2 += __shfl_down(s2, o); }
    __shared__ float red[8];
    int wid = tid >> 6;
    if ((tid & 63) == 0) { red[wid] = s; red[4 + wid] = s2; }
    __syncthreads();
    s  = red[0] + red[1] + red[2] + red[3];
    s2 = red[4] + red[5] + red[6] + red[7];
    float mean = s * (1.0f / 768.0f);
    float var  = s2 * (1.0f / 768.0f) - mean * mean;
    float rinv = rsqrtf(var + 1e-5f);
    float* o_ = out + (size_t)row * DMODEL;
    o_[tid]       = (v0 - mean) * rinv * w[tid]       + b[tid];
    o_[tid + 256] = (v1 - mean) * rinv * w[tid + 256] + b[tid + 256];
    o_[tid + 512] = (v2 - mean) * rinv * w[tid + 512] + b[tid + 512];
}

__global__ __launch_bounds__(256) void ln768_bf16_k(const float* __restrict__ in, ushort_t* __restrict__ out,
                                                    const float* __restrict__ w, const float* __restrict__ b) {
    int row = blockIdx.x, tid = threadIdx.x;
    const float* x = in + (size_t)row * DMODEL;
    float v0 = x[tid], v1 = x[tid + 256], v2 = x[tid + 512];
    float s = v0 + v1 + v2;
    float s2 = v0 * v0 + v1 * v1 + v2 * v2;
    for (int o = 32; o > 0; o >>= 1) { s += __shfl_down(s, o); s2 += __shfl_down(s2, o); }
    __shared__ float red[8];
    int wid = tid >> 6;
    if ((tid & 63) == 0) { red[wid] = s; red[4 + wid] = s2; }
    __syncthreads();
    s  = red[0] + red[1] + red[2] + red[3];
    s2 = red[4] + red[5] + red[6] + red[7];
    float mean = s * (1.0f / 768.0f);
    float var  = s2 * (1.0f / 768.0f) - mean * mean;
    float rinv = rsqrtf(var + 1e-5f);
    ushort_t* o_ = out + (size_t)row * DMODEL;
    o_[tid]       = bf16rn((v0 - mean) * rinv * w[tid]       + b[tid]);
    o_[tid + 256] = bf16rn((v1 - mean) * rinv * w[tid + 256] + b[tid + 256]);
    o_[tid + 512] = bf16rn((v2 - mean) * rinv * w[tid + 512] + b[tid + 512]);
}

// ---------------- pipelined MFMA GEMM, templated tile width ----------------
// BN=128: 256 thr, 4 waves (2x2 of 64x64). BN=256: 512 thr, 8 waves (2x4 of 64x64).
// mode 0: C = r + bias (f32)
// mode 1: OS = bf16(quick_gelu(r + bias))
// mode 3: atomicAdd(C, r (+bias if blockIdx.z==0))   [split-K over gridDim.z]
// mode 4: OS = bf16(r + bias)
template<int BN>
__global__ __launch_bounds__(BN * 2) void gemm_mfma_k(
    const ushort_t* __restrict__ A, const ushort_t* __restrict__ W,
    const float* __restrict__ bias, float* __restrict__ C, ushort_t* __restrict__ OS,
    int M, int N, int K, int mode)
{
    __shared__ ushort_t As[2][128][32];
    __shared__ ushort_t Bs[2][BN][32];
    constexpr int NWN = BN / 64;
    int tid = threadIdx.x;
    int lane = tid & 63;
    int wave = tid >> 6;
    int wm = wave / NWN, wn = wave % NWN;
    int m0 = blockIdx.y * 128, n0 = blockIdx.x * BN;

    int klen = K / gridDim.z;
    int kbeg = blockIdx.z * klen;
    int nt = klen / 32;

    f32x4 acc[4][4];
    #pragma unroll
    for (int i = 0; i < 4; ++i)
        #pragma unroll
        for (int j = 0; j < 4; ++j)
            acc[i][j] = (f32x4){0.f, 0.f, 0.f, 0.f};

    int srow = tid >> 2;                                  // LDS row this lane fills
    int skq  = (((tid & 3) ^ ((tid >> 3) & 3)) * 8);      // pre-swizzled source slot
    const ushort_t *Ap0, *Ap1 = nullptr, *Wp0, *Wp1;
    if constexpr (BN == 128) {
        int ar0 = m0 + srow;      if (ar0 > M - 1) ar0 = M - 1;
        int ar1 = m0 + srow + 64; if (ar1 > M - 1) ar1 = M - 1;
        Ap0 = A + (size_t)ar0 * K + kbeg + skq;
        Ap1 = A + (size_t)ar1 * K + kbeg + skq;
        Wp0 = W + (size_t)(n0 + srow) * K + kbeg + skq;
        Wp1 = W + (size_t)(n0 + srow + 64) * K + kbeg + skq;
    } else {
        int ar0 = m0 + srow;      if (ar0 > M - 1) ar0 = M - 1;   // srow 0..127
        Ap0 = A + (size_t)ar0 * K + kbeg + skq;
        Wp0 = W + (size_t)(n0 + srow) * K + kbeg + skq;
        Wp1 = W + (size_t)(n0 + srow + 128) * K + kbeg + skq;
    }
    char* ldsA = (char*)As + tid * 16;
    char* ldsB = (char*)Bs + tid * 16;
    constexpr int BSTRIDE = BN * 32 * 2;   // bytes per B buffer

    int fr = lane & 15, fq = lane >> 4;
    int rsl = (fq ^ ((fr >> 1) & 3)) * 8;

    // stage tile (buf, k-offset)
    #define STAGE(buf_, ko_) do {                                   \
        if constexpr (BN == 128) {                                  \
            GLL(Ap0 + (ko_), ldsA + (buf_) * 8192);                 \
            GLL(Ap1 + (ko_), ldsA + (buf_) * 8192 + 4096);          \
            GLL(Wp0 + (ko_), ldsB + (buf_) * 8192);                 \
            GLL(Wp1 + (ko_), ldsB + (buf_) * 8192 + 4096);          \
        } else {                                                    \
            GLL(Ap0 + (ko_), ldsA + (buf_) * 8192);                 \
            GLL(Wp0 + (ko_), ldsB + (buf_) * BSTRIDE);              \
            GLL(Wp1 + (ko_), ldsB + (buf_) * BSTRIDE + 8192);       \
        }                                                           \
    } while (0)

    STAGE(0, 0);

    for (int t = 0; t < nt; ++t) {
        int cur = t & 1;
        if (t + 1 < nt) {
            STAGE(cur ^ 1, (size_t)(t + 1) * 32);
            if constexpr (BN == 128) {
                asm volatile("s_waitcnt vmcnt(4)\n\ts_barrier" ::: "memory");
            } else {
                asm volatile("s_waitcnt vmcnt(3)\n\ts_barrier" ::: "memory");
            }
        } else {
            asm volatile("s_waitcnt vmcnt(0)\n\ts_barrier" ::: "memory");
        }
        bf16x8 a[4], b[4];
        #pragma unroll
        for (int fm = 0; fm < 4; ++fm)
            a[fm] = *(const bf16x8*)&As[cur][wm * 64 + fm * 16 + fr][rsl];
        #pragma unroll
        for (int fn = 0; fn < 4; ++fn)
            b[fn] = *(const bf16x8*)&Bs[cur][wn * 64 + fn * 16 + fr][rsl];
        #pragma unroll
        for (int fm = 0; fm < 4; ++fm)
            #pragma unroll
            for (int fn = 0; fn < 4; ++fn)
                acc[fm][fn] = __builtin_amdgcn_mfma_f32_16x16x32_bf16(a[fm], b[fn], acc[fm][fn], 0, 0, 0);
        asm volatile("s_barrier" ::: "memory");
    }
    #undef STAGE

    // epilogue: D col = lane&15 (fr), row = fq*4 + j
    #pragma unroll
    for (int fn = 0; fn < 4; ++fn) {
        int ccol = n0 + wn * 64 + fn * 16 + fr;
        float bv = bias ? bias[ccol] : 0.f;
        if (mode == 3 && blockIdx.z != 0) bv = 0.f;
        #pragma unroll
        for (int fm = 0; fm < 4; ++fm) {
            int crow0 = m0 + wm * 64 + fm * 16 + fq * 4;
            #pragma unroll
            for (int j = 0; j < 4; ++j) {
                int row = crow0 + j;
                if (row < M) {
                    float v = acc[fm][fn][j] + bv;
                    if (mode == 0) {
                        C[(size_t)row * N + ccol] = v;
                    } else if (mode == 3) {
                        atomicAdd(&C[(size_t)row * N + ccol], v);
                    } else if (mode == 4) {
                        OS[(size_t)row * N + ccol] = bf16rn(v);
                    } else {
                        v = v / (1.0f + expf(-1.702f * v));
                        OS[(size_t)row * N + ccol] = bf16rn(v);
                    }
                }
            }
        }
    }
}

// ---------------- fused MFMA flash attention, swapped-QK^T, 8 waves ----------------
__global__ __launch_bounds__(512, 4) void attn_fused_k(
    const ushort_t* __restrict__ qkvb, ushort_t* __restrict__ out,
    const float* __restrict__ addition, int qoff)
{
    __shared__ ushort_t Ks[208][72];
    __shared__ ushort_t Vt[64][232];
    __shared__ ushort_t Pb[8][2][16][40];
    int tid = threadIdx.x;
    int bh = blockIdx.x;
    int b = bh / NHEAD, hh = bh - b * NHEAD;
    const ushort_t* base = qkvb + (size_t)b * NTOK * DQKV + hh * HDIM;

    int lane = tid & 63, wave = tid >> 6;
    int fr = lane & 15, fq = lane >> 4;
    int nq = (wave + 8 < 13) ? 2 : 1;

    bf16x8 qf[2][2];
    #pragma unroll
    for (int t = 0; t < 2; ++t) {
        if (t < nq) {
            int qrow = (wave + t * 8) * 16 + fr; if (qrow > NTOK - 1) qrow = NTOK - 1;
            const ushort_t* qp = base + (size_t)qrow * DQKV + qoff + fq * 8;
            qf[t][0] = *(const bf16x8*)qp;
            qf[t][1] = *(const bf16x8*)(qp + 32);
        }
    }

    {
        int tt = tid >> 4, dq = tid & 15;
        #pragma unroll
        for (int pass = 0; pass < 7; ++pass) {
            int t = pass * 32 + tt;
            if (t < 208) {
                ushort4 kv = {0, 0, 0, 0}, vv = {0, 0, 0, 0};
                if (t < NTOK) {
                    kv = *(const ushort4*)(base + (size_t)t * DQKV + DMODEL + dq * 4);
                    vv = *(const ushort4*)(base + (size_t)t * DQKV + 2 * DMODEL + dq * 4);
                }
                *(ushort4*)&Ks[t][dq * 4] = kv;
                Vt[dq * 4 + 0][t] = vv.x;
                Vt[dq * 4 + 1][t] = vv.y;
                Vt[dq * 4 + 2][t] = vv.z;
                Vt[dq * 4 + 3][t] = vv.w;
            }
        }
        for (int z = tid; z < 64 * 24; z += 512) Vt[z / 24][208 + z % 24] = 0;
    }
    __syncthreads();

    for (int t = 0; t < nq; ++t) {
        int qt = wave + t * 8;
        int i0 = qt * 16;
        int irow = i0 + fr; if (irow > NTOK - 1) irow = NTOK - 1;

        f32x4 s[13];
        #pragma unroll
        for (int jt = 0; jt < 13; ++jt) {
            bf16x8 k0 = *(const bf16x8*)&Ks[jt * 16 + fr][fq * 8];
            bf16x8 k1 = *(const bf16x8*)&Ks[jt * 16 + fr][32 + fq * 8];
            f32x4 a = {0.f, 0.f, 0.f, 0.f};
            a = __builtin_amdgcn_mfma_f32_16x16x32_bf16(k0, qf[t][0], a, 0, 0, 0);
            a = __builtin_amdgcn_mfma_f32_16x16x32_bf16(k1, qf[t][1], a, 0, 0, 0);
            s[jt] = a;
        }

        float mx = -1e30f;
        #pragma unroll
        for (int jt = 0; jt < 13; ++jt) {
            int jb = jt * 16 + fq * 4;
            #pragma unroll
            for (int jj = 0; jj < 4; ++jj) {
                int j = jb + jj;
                float v = s[jt][jj] * 0.125f;
                if (addition) v += addition[irow * NTOK + (j < NTOK ? j : NTOK - 1)];
                if (j >= NTOK) v = -1e30f;
                s[jt][jj] = v;
                mx = fmaxf(mx, v);
            }
        }
        mx = fmaxf(mx, __shfl_xor(mx, 16));
        mx = fmaxf(mx, __shfl_xor(mx, 32));
        float sum = 0.f;
        #pragma unroll
        for (int jt = 0; jt < 13; ++jt)
            #pragma unroll
            for (int jj = 0; jj < 4; ++jj) {
                float e = __expf(s[jt][jj] - mx);
                s[jt][jj] = e;
                sum += e;
            }
        sum += __shfl_xor(sum, 16);
        sum += __shfl_xor(sum, 32);
        float inv = 1.0f / sum;

        f32x4 o4[4];
        #pragma unroll
        for (int dt = 0; dt < 4; ++dt) o4[dt] = (f32x4){0.f, 0.f, 0.f, 0.f};

        #define WRITE_P(st_, buf_) do {                                              \
            int jA = 2 * (st_), jB = jA + 1;                                         \
            ushort4 wa = {bf16rn(s[jA][0] * inv), bf16rn(s[jA][1] * inv),            \
                          bf16rn(s[jA][2] * inv), bf16rn(s[jA][3] * inv)};           \
            ushort4 wb = {0, 0, 0, 0};                                               \
            if (jB < 13) wb = (ushort4){bf16rn(s[jB][0] * inv), bf16rn(s[jB][1] * inv), \
                                        bf16rn(s[jB][2] * inv), bf16rn(s[jB][3] * inv)}; \
            *(ushort4*)&Pb[wave][buf_][fr][fq * 4] = wa;                             \
            *(ushort4*)&Pb[wave][buf_][fr][16 + fq * 4] = wb;                        \
        } while (0)

        WRITE_P(0, 0);
        for (int st = 0; st < 7; ++st) {
            asm volatile("s_waitcnt lgkmcnt(0)" ::: "memory");
            bf16x8 pa = *(const bf16x8*)&Pb[wave][st & 1][fr][fq * 8];
            bf16x8 vf0 = *(const bf16x8*)&Vt[0 * 16 + fr][st * 32 + fq * 8];
            bf16x8 vf1 = *(const bf16x8*)&Vt[1 * 16 + fr][st * 32 + fq * 8];
            bf16x8 vf2 = *(const bf16x8*)&Vt[2 * 16 + fr][st * 32 + fq * 8];
            bf16x8 vf3 = *(const bf16x8*)&Vt[3 * 16 + fr][st * 32 + fq * 8];
            if (st < 6) WRITE_P(st + 1, (st + 1) & 1);
            o4[0] = __builtin_amdgcn_mfma_f32_16x16x32_bf16(pa, vf0, o4[0], 0, 0, 0);
            o4[1] = __builtin_amdgcn_mfma_f32_16x16x32_bf16(pa, vf1, o4[1], 0, 0, 0);
            o4[2] = __builtin_amdgcn_mfma_f32_16x16x32_bf16(pa, vf2, o4[2], 0, 0, 0);
            o4[3] = __builtin_amdgcn_mfma_f32_16x16x32_bf16(pa, vf3, o4[3], 0, 0, 0);
        }
        #undef WRITE_P

        #pragma unroll
        for (int jj = 0; jj < 4; ++jj) {
            int ir = i0 + fq * 4 + jj;
            if (ir < NTOK) {
                ushort_t* op = out + ((size_t)(b * NTOK + ir)) * DMODEL + hh * HDIM + fr;
                #pragma unroll
                for (int dt = 0; dt < 4; ++dt)
                    op[dt * 16] = bf16rn(o4[dt][jj]);
            }
        }
    }
}

// ---------------- launch ----------------
extern "C" void kernel_launch(void* const* d_in, const int* in_sizes, int n_in,
                              void* d_out, int out_size, void* d_ws, size_t ws_size,
                              hipStream_t stream) {
    const float* x        = (const float*)d_in[0];
    const float* conv1_w  = (const float*)d_in[1];
    const float* cls      = (const float*)d_in[2];
    const float* pos      = (const float*)d_in[3];
    const float* ln_pre_w = (const float*)d_in[4];
    const float* ln_pre_b = (const float*)d_in[5];
    const float* in_proj_w  = (const float*)d_in[6];
    const float* in_proj_b  = (const float*)d_in[7];
    const float* out_proj_w = (const float*)d_in[8];
    const float* out_proj_b = (const float*)d_in[9];
    const float* ln1_w = (const float*)d_in[10];
    const float* ln1_b = (const float*)d_in[11];
    const float* ln2_w = (const float*)d_in[12];
    const float* ln2_b = (const float*)d_in[13];
    const float* fc_w  = (const float*)d_in[14];
    const float* fc_b  = (const float*)d_in[15];
    const float* cproj_w = (const float*)d_in[16];
    const float* cproj_b = (const float*)d_in[17];
    const float* ln_post_w = (const float*)d_in[18];
    const float* ln_post_b = (const float*)d_in[19];
    const float* proj = (const float*)d_in[20];
    float* out = (float*)d_out;

    float* ws   = (float*)d_ws;
    float* h    = ws + WS_H;
    float* ctmp = ws + WS_QKVB;
    ushort_t* qkvb = (ushort_t*)(ws + WS_QKVB);
    ushort_t* gb   = (ushort_t*)(ws + WS_GB);
    ushort_t* tb   = (ushort_t*)(ws + WS_TB);
    ushort_t* wl   = (ushort_t*)(ws + WS_WL);
    ushort_t* pTs  = (ushort_t*)(ws + WS_PTS);
    float* add  = ws + WS_ADD;

    im2col_bf16_k<<<(CROWS * DMODEL / 4 + 255) / 256, 256, 0, stream>>>(x, tb);
    cvt_w_k<<<(DMODEL * DMODEL / 4 + 255) / 256, 256, 0, stream>>>(conv1_w, wl, DMODEL * DMODEL);
    gemm_mfma_k<128><<<dim3(DMODEL / 128, (CROWS + 127) / 128), 256, 0, stream>>>(
        tb, wl, nullptr, ctmp, nullptr, CROWS, DMODEL, DMODEL, 0);
    embed_k<<<(ROWS * DMODEL + 255) / 256, 256, 0, stream>>>(ctmp, cls, pos, h);
    ln768_k<<<ROWS, 256, 0, stream>>>(h, h, ln_pre_w, ln_pre_b);
    gauss_k<<<(NTOK * NTOK + 255) / 256, 256, 0, stream>>>(add);
    cvt_pT_k<<<(DOUT * DMODEL + 255) / 256, 256, 0, stream>>>(proj, pTs);

    const int GY = (ROWS + 127) / 128;  // 50
    for (int l = 0; l < NLAYER; ++l) {
        cvt_layer_k<<<(int)(WTOT / 4 / 256), 256, 0, stream>>>(
            in_proj_w + (size_t)l * DQKV * DMODEL, out_proj_w + (size_t)l * DMODEL * DMODEL,
            fc_w + (size_t)l * DFF * DMODEL, cproj_w + (size_t)l * DMODEL * DFF, wl);
        ln768_bf16_k<<<ROWS, 256, 0, stream>>>(h, tb, ln1_w + l * DMODEL, ln1_b + l * DMODEL);
        gemm_mfma_k<256><<<dim3(DQKV / 256, GY), 512, 0, stream>>>(
            tb, wl + WOFF_IN, in_proj_b + (size_t)l * DQKV, nullptr, qkvb, ROWS, DQKV, DMODEL, 4);
        bool nac = (l == NLAYER - 1);
        attn_fused_k<<<NBH, 512, 0, stream>>>(qkvb, tb, nac ? add : nullptr, nac ? DMODEL : 0);
        gemm_mfma_k<128><<<dim3(DMODEL / 128, GY, 2), 256, 0, stream>>>(
            tb, wl + WOFF_OUT, out_proj_b + (size_t)l * DMODEL, h, nullptr, ROWS, DMODEL, DMODEL, 3);
        ln768_bf16_k<<<ROWS, 256, 0, stream>>>(h, tb, ln2_w + l * DMODEL, ln2_b + l * DMODEL);
        gemm_mfma_k<256><<<dim3(DFF / 256, GY), 512, 0, stream>>>(
            tb, wl + WOFF_FC, fc_b + (size_t)l * DFF, nullptr, gb, ROWS, DFF, DMODEL, 1);
        gemm_mfma_k<256><<<dim3(DMODEL / 256, GY, 4), 512, 0, stream>>>(
            gb, wl + WOFF_CP, cproj_b + (size_t)l * DMODEL, h, nullptr, ROWS, DMODEL, DFF, 3);
    }

    ln768_bf16_k<<<ROWS, 256, 0, stream>>>(h, tb, ln_post_w, ln_post_b);
    gemm_mfma_k<128><<<dim3(DOUT / 128, GY), 256, 0, stream>>>(
        tb, pTs, nullptr, out, nullptr, ROWS, DOUT, DMODEL, 0);
}

// Round 8
// 3524.751 us; speedup vs baseline: 1.0642x; 1.0642x over previous
//
#include <hip/hip_runtime.h>
#include <hip/hip_bf16.h>
#include <math.h>

// ---------------- problem constants ----------------
#define BATCH 32
#define NTOK  197
#define NPATCH 196
#define DMODEL 768
#define NLAYER 12
#define NHEAD 12
#define HDIM  64
#define ROWS  (BATCH*NTOK)     // 6304
#define CROWS (BATCH*NPATCH)   // 6272
#define DFF   3072
#define DQKV  2304
#define DOUT  512
#define NBH   (BATCH*NHEAD)

// per-layer weight slab offsets (bf16 elems)
#define WOFF_IN   ((size_t)0)
#define WOFF_OUT  ((size_t)(DQKV*DMODEL))
#define WOFF_FC   (WOFF_OUT + (size_t)(DMODEL*DMODEL))
#define WOFF_CP   (WOFF_FC + (size_t)(DFF*DMODEL))
#define WTOT      (WOFF_CP + (size_t)(DMODEL*DFF))

// workspace layout (float units)
#define WS_H    ((size_t)0)
#define WS_QKVB (WS_H + (size_t)ROWS*DMODEL)
#define WS_GB   (WS_QKVB + (size_t)ROWS*DQKV/2)
#define WS_TB   (WS_GB + (size_t)ROWS*DFF/2)
#define WS_WL   (WS_TB + (size_t)ROWS*DMODEL/2)
#define WS_PTS  (WS_WL + WTOT/2)
#define WS_ADD  (WS_PTS + (size_t)DOUT*DMODEL/2)

typedef unsigned short ushort_t;
typedef __attribute__((ext_vector_type(8))) short bf16x8;
typedef __attribute__((ext_vector_type(4))) float f32x4;

__device__ inline ushort_t bf16rn(float x) {
    uint32_t u = __builtin_bit_cast(uint32_t, x);
    uint32_t r = (u + 0x7FFFu + ((u >> 16) & 1u)) >> 16;
    return (ushort_t)r;
}

#define GLL(src, dst) __builtin_amdgcn_global_load_lds( \
    (const __attribute__((address_space(1))) void*)(src), \
    (__attribute__((address_space(3))) void*)(dst), 16, 0, 0)

// ---------------- small kernels ----------------

__global__ void im2col_bf16_k(const float* __restrict__ x, ushort_t* __restrict__ out) {
    int idx = blockIdx.x * 256 + threadIdx.x;
    if (idx >= CROWS * DMODEL / 4) return;
    int r  = idx / (DMODEL / 4);
    int k4 = (idx - r * (DMODEL / 4)) * 4;
    int b = r / NPATCH, p = r - b * NPATCH;
    int py = p / 14, px = p - py * 14;
    int c = k4 >> 8, rem = k4 & 255, i = rem >> 4, j = rem & 15;
    const float* xp = x + (((size_t)(b * 3 + c) * 224) + py * 16 + i) * 224 + px * 16 + j;
    float4 v = *(const float4*)xp;
    ushort4 hv = {bf16rn(v.x), bf16rn(v.y), bf16rn(v.z), bf16rn(v.w)};
    *(ushort4*)(out + (size_t)r * DMODEL + k4) = hv;
}

__global__ void cvt_w_k(const float* __restrict__ W, ushort_t* __restrict__ out, int NK) {
    int idx = (blockIdx.x * 256 + threadIdx.x) * 4;
    if (idx >= NK) return;
    float4 v = *(const float4*)(W + idx);
    ushort4 hv = {bf16rn(v.x), bf16rn(v.y), bf16rn(v.z), bf16rn(v.w)};
    *(ushort4*)(out + idx) = hv;
}

__global__ void cvt_layer_k(const float* __restrict__ inW, const float* __restrict__ outW,
                            const float* __restrict__ fcW, const float* __restrict__ cpW,
                            ushort_t* __restrict__ wl) {
    size_t idx = ((size_t)blockIdx.x * 256 + threadIdx.x) * 4;
    if (idx >= WTOT) return;
    const float* src; size_t off;
    if (idx < WOFF_OUT)      { src = inW;  off = idx; }
    else if (idx < WOFF_FC)  { src = outW; off = idx - WOFF_OUT; }
    else if (idx < WOFF_CP)  { src = fcW;  off = idx - WOFF_FC; }
    else                     { src = cpW;  off = idx - WOFF_CP; }
    float4 v = *(const float4*)(src + off);
    ushort4 hv = {bf16rn(v.x), bf16rn(v.y), bf16rn(v.z), bf16rn(v.w)};
    *(ushort4*)(wl + idx) = hv;
}

__global__ void cvt_pT_k(const float* __restrict__ proj, ushort_t* __restrict__ out) {
    int idx = blockIdx.x * 256 + threadIdx.x;
    if (idx >= DOUT * DMODEL) return;
    int n = idx / DMODEL, k = idx - n * DMODEL;
    out[(size_t)n * DMODEL + k] = bf16rn(proj[(size_t)k * DOUT + n]);
}

__global__ void embed_k(const float* __restrict__ conv, const float* __restrict__ cls,
                        const float* __restrict__ pos, float* __restrict__ h) {
    int idx = blockIdx.x * 256 + threadIdx.x;
    if (idx >= ROWS * DMODEL) return;
    int r = idx / DMODEL, d = idx - r * DMODEL;
    int b = r / NTOK, tok = r - b * NTOK;
    float v = (tok == 0) ? cls[d] : conv[((size_t)(b * NPATCH + tok - 1)) * DMODEL + d];
    h[idx] = v + pos[(size_t)tok * DMODEL + d];
}

__global__ void gauss_k(float* __restrict__ add) {
    int idx = blockIdx.x * 256 + threadIdx.x;
    if (idx >= NTOK * NTOK) return;
    int i = idx / NTOK, j = idx - i * NTOK;
    float v = 0.f;
    if (i > 0 && j > 0) {
        int p = i - 1, q = j - 1;
        int di = q / 14 - p / 14;
        int dj = q % 14 - p % 14;
        v = expf(-(float)(di * di + dj * dj) * 0.02f);
    }
    add[idx] = v;
}

__global__ __launch_bounds__(256) void ln768_k(const float* __restrict__ in, float* __restrict__ out,
                                               const float* __restrict__ w, const float* __restrict__ b) {
    int row = blockIdx.x, tid = threadIdx.x;
    const float* x = in + (size_t)row * DMODEL;
    float v0 = x[tid], v1 = x[tid + 256], v2 = x[tid + 512];
    float s = v0 + v1 + v2;
    float s2 = v0 * v0 + v1 * v1 + v2 * v2;
    for (int o = 32; o > 0; o >>= 1) { s += __shfl_down(s, o); s2 += __shfl_down(s2, o); }
    __shared__ float red[8];
    int wid = tid >> 6;
    if ((tid & 63) == 0) { red[wid] = s; red[4 + wid] = s2; }
    __syncthreads();
    s  = red[0] + red[1] + red[2] + red[3];
    s2 = red[4] + red[5] + red[6] + red[7];
    float mean = s * (1.0f / 768.0f);
    float var  = s2 * (1.0f / 768.0f) - mean * mean;
    float rinv = rsqrtf(var + 1e-5f);
    float* o_ = out + (size_t)row * DMODEL;
    o_[tid]       = (v0 - mean) * rinv * w[tid]       + b[tid];
    o_[tid + 256] = (v1 - mean) * rinv * w[tid + 256] + b[tid + 256];
    o_[tid + 512] = (v2 - mean) * rinv * w[tid + 512] + b[tid + 512];
}

__global__ __launch_bounds__(256) void ln768_bf16_k(const float* __restrict__ in, ushort_t* __restrict__ out,
                                                    const float* __restrict__ w, const float* __restrict__ b) {
    int row = blockIdx.x, tid = threadIdx.x;
    const float* x = in + (size_t)row * DMODEL;
    float v0 = x[tid], v1 = x[tid + 256], v2 = x[tid + 512];
    float s = v0 + v1 + v2;
    float s2 = v0 * v0 + v1 * v1 + v2 * v2;
    for (int o = 32; o > 0; o >>= 1) { s += __shfl_down(s, o); s2 += __shfl_down(s2, o); }
    __shared__ float red[8];
    int wid = tid >> 6;
    if ((tid & 63) == 0) { red[wid] = s; red[4 + wid] = s2; }
    __syncthreads();
    s  = red[0] + red[1] + red[2] + red[3];
    s2 = red[4] + red[5] + red[6] + red[7];
    float mean = s * (1.0f / 768.0f);
    float var  = s2 * (1.0f / 768.0f) - mean * mean;
    float rinv = rsqrtf(var + 1e-5f);
    ushort_t* o_ = out + (size_t)row * DMODEL;
    o_[tid]       = bf16rn((v0 - mean) * rinv * w[tid]       + b[tid]);
    o_[tid + 256] = bf16rn((v1 - mean) * rinv * w[tid + 256] + b[tid + 256]);
    o_[tid + 512] = bf16rn((v2 - mean) * rinv * w[tid + 512] + b[tid + 512]);
}

// ---------------- triple-buffered MFMA GEMM:  C[M,N] (+)= A[M,K] @ W[N,K]^T ----------------
// grid: (x = m-block, y = n-block, z = split-K).  2 tiles prefetched ahead (vmcnt(8)).
// mode 0: C = r + bias (f32)
// mode 1: OS = bf16(quick_gelu(r + bias))
// mode 3: atomicAdd(C, r (+bias if blockIdx.z==0))
// mode 4: OS = bf16(r + bias)
__global__ __launch_bounds__(256) void gemm_mfma_k(
    const ushort_t* __restrict__ A, const ushort_t* __restrict__ W,
    const float* __restrict__ bias, float* __restrict__ C, ushort_t* __restrict__ OS,
    int M, int N, int K, int mode)
{
    __shared__ ushort_t As[3][128][32];
    __shared__ ushort_t Bs[3][128][32];
    int tid = threadIdx.x;
    int lane = tid & 63;
    int wave = tid >> 6;
    int wm = wave >> 1, wn = wave & 1;
    int m0 = blockIdx.x * 128, n0 = blockIdx.y * 128;

    int klen = K / gridDim.z;
    int kbeg = blockIdx.z * klen;
    int nt = klen / 32;

    f32x4 acc[4][4];
    #pragma unroll
    for (int i = 0; i < 4; ++i)
        #pragma unroll
        for (int j = 0; j < 4; ++j)
            acc[i][j] = (f32x4){0.f, 0.f, 0.f, 0.f};

    int srow = tid >> 2;
    int skq  = (((tid & 3) ^ ((tid >> 3) & 3)) * 8);      // pre-swizzled source slot
    int ar0 = m0 + srow;      if (ar0 > M - 1) ar0 = M - 1;
    int ar1 = m0 + srow + 64; if (ar1 > M - 1) ar1 = M - 1;
    const ushort_t* Ap0 = A + (size_t)ar0 * K + kbeg + skq;
    const ushort_t* Ap1 = A + (size_t)ar1 * K + kbeg + skq;
    const ushort_t* Wp0 = W + (size_t)(n0 + srow) * K + kbeg + skq;
    const ushort_t* Wp1 = W + (size_t)(n0 + srow + 64) * K + kbeg + skq;
    char* ldsA = (char*)As + tid * 16;
    char* ldsB = (char*)Bs + tid * 16;

    int fr = lane & 15, fq = lane >> 4;
    int rsl = (fq ^ ((fr >> 1) & 3)) * 8;                 // swizzled read slot

    #define STAGE(buf_, ko_) do {                         \
        GLL(Ap0 + (ko_), ldsA + (buf_) * 8192);           \
        GLL(Ap1 + (ko_), ldsA + (buf_) * 8192 + 4096);    \
        GLL(Wp0 + (ko_), ldsB + (buf_) * 8192);           \
        GLL(Wp1 + (ko_), ldsB + (buf_) * 8192 + 4096);    \
    } while (0)

    STAGE(0, 0);
    STAGE(1, 32);

    for (int t = 0; t < nt; ++t) {
        int cur = t % 3;
        if (t + 2 < nt) {
            STAGE((t + 2) % 3, (size_t)(t + 2) * 32);
            asm volatile("s_waitcnt vmcnt(8)\n\ts_barrier" ::: "memory");
        } else if (t + 1 < nt) {
            asm volatile("s_waitcnt vmcnt(4)\n\ts_barrier" ::: "memory");
        } else {
            asm volatile("s_waitcnt vmcnt(0)\n\ts_barrier" ::: "memory");
        }
        bf16x8 a[4], b[4];
        #pragma unroll
        for (int fm = 0; fm < 4; ++fm)
            a[fm] = *(const bf16x8*)&As[cur][wm * 64 + fm * 16 + fr][rsl];
        #pragma unroll
        for (int fn = 0; fn < 4; ++fn)
            b[fn] = *(const bf16x8*)&Bs[cur][wn * 64 + fn * 16 + fr][rsl];
        #pragma unroll
        for (int fm = 0; fm < 4; ++fm)
            #pragma unroll
            for (int fn = 0; fn < 4; ++fn)
                acc[fm][fn] = __builtin_amdgcn_mfma_f32_16x16x32_bf16(a[fm], b[fn], acc[fm][fn], 0, 0, 0);
        asm volatile("s_barrier" ::: "memory");
    }
    #undef STAGE

    // epilogue: D col = lane&15 (fr), row = fq*4 + j
    #pragma unroll
    for (int fn = 0; fn < 4; ++fn) {
        int ccol = n0 + wn * 64 + fn * 16 + fr;
        float bv = bias ? bias[ccol] : 0.f;
        if (mode == 3 && blockIdx.z != 0) bv = 0.f;
        #pragma unroll
        for (int fm = 0; fm < 4; ++fm) {
            int crow0 = m0 + wm * 64 + fm * 16 + fq * 4;
            #pragma unroll
            for (int j = 0; j < 4; ++j) {
                int row = crow0 + j;
                if (row < M) {
                    float v = acc[fm][fn][j] + bv;
                    if (mode == 0) {
                        C[(size_t)row * N + ccol] = v;
                    } else if (mode == 3) {
                        atomicAdd(&C[(size_t)row * N + ccol], v);
                    } else if (mode == 4) {
                        OS[(size_t)row * N + ccol] = bf16rn(v);
                    } else {
                        v = v / (1.0f + expf(-1.702f * v));
                        OS[(size_t)row * N + ccol] = bf16rn(v);
                    }
                }
            }
        }
    }
}

// ---------------- fused MFMA flash attention, swapped-QK^T, 8 waves ----------------
__global__ __launch_bounds__(512, 4) void attn_fused_k(
    const ushort_t* __restrict__ qkvb, ushort_t* __restrict__ out,
    const float* __restrict__ addition, int qoff)
{
    __shared__ ushort_t Ks[208][72];
    __shared__ ushort_t Vt[64][232];
    __shared__ ushort_t Pb[8][2][16][40];
    int tid = threadIdx.x;
    int bh = blockIdx.x;
    int b = bh / NHEAD, hh = bh - b * NHEAD;
    const ushort_t* base = qkvb + (size_t)b * NTOK * DQKV + hh * HDIM;

    int lane = tid & 63, wave = tid >> 6;
    int fr = lane & 15, fq = lane >> 4;
    int nq = (wave + 8 < 13) ? 2 : 1;

    bf16x8 qf[2][2];
    #pragma unroll
    for (int t = 0; t < 2; ++t) {
        if (t < nq) {
            int qrow = (wave + t * 8) * 16 + fr; if (qrow > NTOK - 1) qrow = NTOK - 1;
            const ushort_t* qp = base + (size_t)qrow * DQKV + qoff + fq * 8;
            qf[t][0] = *(const bf16x8*)qp;
            qf[t][1] = *(const bf16x8*)(qp + 32);
        }
    }

    {
        int tt = tid >> 4, dq = tid & 15;
        #pragma unroll
        for (int pass = 0; pass < 7; ++pass) {
            int t = pass * 32 + tt;
            if (t < 208) {
                ushort4 kv = {0, 0, 0, 0}, vv = {0, 0, 0, 0};
                if (t < NTOK) {
                    kv = *(const ushort4*)(base + (size_t)t * DQKV + DMODEL + dq * 4);
                    vv = *(const ushort4*)(base + (size_t)t * DQKV + 2 * DMODEL + dq * 4);
                }
                *(ushort4*)&Ks[t][dq * 4] = kv;
                Vt[dq * 4 + 0][t] = vv.x;
                Vt[dq * 4 + 1][t] = vv.y;
                Vt[dq * 4 + 2][t] = vv.z;
                Vt[dq * 4 + 3][t] = vv.w;
            }
        }
        for (int z = tid; z < 64 * 24; z += 512) Vt[z / 24][208 + z % 24] = 0;
    }
    __syncthreads();

    for (int t = 0; t < nq; ++t) {
        int qt = wave + t * 8;
        int i0 = qt * 16;
        int irow = i0 + fr; if (irow > NTOK - 1) irow = NTOK - 1;

        f32x4 s[13];
        #pragma unroll
        for (int jt = 0; jt < 13; ++jt) {
            bf16x8 k0 = *(const bf16x8*)&Ks[jt * 16 + fr][fq * 8];
            bf16x8 k1 = *(const bf16x8*)&Ks[jt * 16 + fr][32 + fq * 8];
            f32x4 a = {0.f, 0.f, 0.f, 0.f};
            a = __builtin_amdgcn_mfma_f32_16x16x32_bf16(k0, qf[t][0], a, 0, 0, 0);
            a = __builtin_amdgcn_mfma_f32_16x16x32_bf16(k1, qf[t][1], a, 0, 0, 0);
            s[jt] = a;
        }

        float mx = -1e30f;
        #pragma unroll
        for (int jt = 0; jt < 13; ++jt) {
            int jb = jt * 16 + fq * 4;
            #pragma unroll
            for (int jj = 0; jj < 4; ++jj) {
                int j = jb + jj;
                float v = s[jt][jj] * 0.125f;
                if (addition) v += addition[irow * NTOK + (j < NTOK ? j : NTOK - 1)];
                if (j >= NTOK) v = -1e30f;
                s[jt][jj] = v;
                mx = fmaxf(mx, v);
            }
        }
        mx = fmaxf(mx, __shfl_xor(mx, 16));
        mx = fmaxf(mx, __shfl_xor(mx, 32));
        float sum = 0.f;
        #pragma unroll
        for (int jt = 0; jt < 13; ++jt)
            #pragma unroll
            for (int jj = 0; jj < 4; ++jj) {
                float e = __expf(s[jt][jj] - mx);
                s[jt][jj] = e;
                sum += e;
            }
        sum += __shfl_xor(sum, 16);
        sum += __shfl_xor(sum, 32);
        float inv = 1.0f / sum;

        f32x4 o4[4];
        #pragma unroll
        for (int dt = 0; dt < 4; ++dt) o4[dt] = (f32x4){0.f, 0.f, 0.f, 0.f};

        #define WRITE_P(st_, buf_) do {                                              \
            int jA = 2 * (st_), jB = jA + 1;                                         \
            ushort4 wa = {bf16rn(s[jA][0] * inv), bf16rn(s[jA][1] * inv),            \
                          bf16rn(s[jA][2] * inv), bf16rn(s[jA][3] * inv)};           \
            ushort4 wb = {0, 0, 0, 0};                                               \
            if (jB < 13) wb = (ushort4){bf16rn(s[jB][0] * inv), bf16rn(s[jB][1] * inv), \
                                        bf16rn(s[jB][2] * inv), bf16rn(s[jB][3] * inv)}; \
            *(ushort4*)&Pb[wave][buf_][fr][fq * 4] = wa;                             \
            *(ushort4*)&Pb[wave][buf_][fr][16 + fq * 4] = wb;                        \
        } while (0)

        WRITE_P(0, 0);
        for (int st = 0; st < 7; ++st) {
            asm volatile("s_waitcnt lgkmcnt(0)" ::: "memory");
            bf16x8 pa = *(const bf16x8*)&Pb[wave][st & 1][fr][fq * 8];
            bf16x8 vf0 = *(const bf16x8*)&Vt[0 * 16 + fr][st * 32 + fq * 8];
            bf16x8 vf1 = *(const bf16x8*)&Vt[1 * 16 + fr][st * 32 + fq * 8];
            bf16x8 vf2 = *(const bf16x8*)&Vt[2 * 16 + fr][st * 32 + fq * 8];
            bf16x8 vf3 = *(const bf16x8*)&Vt[3 * 16 + fr][st * 32 + fq * 8];
            if (st < 6) WRITE_P(st + 1, (st + 1) & 1);
            o4[0] = __builtin_amdgcn_mfma_f32_16x16x32_bf16(pa, vf0, o4[0], 0, 0, 0);
            o4[1] = __builtin_amdgcn_mfma_f32_16x16x32_bf16(pa, vf1, o4[1], 0, 0, 0);
            o4[2] = __builtin_amdgcn_mfma_f32_16x16x32_bf16(pa, vf2, o4[2], 0, 0, 0);
            o4[3] = __builtin_amdgcn_mfma_f32_16x16x32_bf16(pa, vf3, o4[3], 0, 0, 0);
        }
        #undef WRITE_P

        #pragma unroll
        for (int jj = 0; jj < 4; ++jj) {
            int ir = i0 + fq * 4 + jj;
            if (ir < NTOK) {
                ushort_t* op = out + ((size_t)(b * NTOK + ir)) * DMODEL + hh * HDIM + fr;
                #pragma unroll
                for (int dt = 0; dt < 4; ++dt)
                    op[dt * 16] = bf16rn(o4[dt][jj]);
            }
        }
    }
}

// ---------------- launch ----------------
extern "C" void kernel_launch(void* const* d_in, const int* in_sizes, int n_in,
                              void* d_out, int out_size, void* d_ws, size_t ws_size,
                              hipStream_t stream) {
    const float* x        = (const float*)d_in[0];
    const float* conv1_w  = (const float*)d_in[1];
    const float* cls      = (const float*)d_in[2];
    const float* pos      = (const float*)d_in[3];
    const float* ln_pre_w = (const float*)d_in[4];
    const float* ln_pre_b = (const float*)d_in[5];
    const float* in_proj_w  = (const float*)d_in[6];
    const float* in_proj_b  = (const float*)d_in[7];
    const float* out_proj_w = (const float*)d_in[8];
    const float* out_proj_b = (const float*)d_in[9];
    const float* ln1_w = (const float*)d_in[10];
    const float* ln1_b = (const float*)d_in[11];
    const float* ln2_w = (const float*)d_in[12];
    const float* ln2_b = (const float*)d_in[13];
    const float* fc_w  = (const float*)d_in[14];
    const float* fc_b  = (const float*)d_in[15];
    const float* cproj_w = (const float*)d_in[16];
    const float* cproj_b = (const float*)d_in[17];
    const float* ln_post_w = (const float*)d_in[18];
    const float* ln_post_b = (const float*)d_in[19];
    const float* proj = (const float*)d_in[20];
    float* out = (float*)d_out;

    float* ws   = (float*)d_ws;
    float* h    = ws + WS_H;
    float* ctmp = ws + WS_QKVB;
    ushort_t* qkvb = (ushort_t*)(ws + WS_QKVB);
    ushort_t* gb   = (ushort_t*)(ws + WS_GB);
    ushort_t* tb   = (ushort_t*)(ws + WS_TB);
    ushort_t* wl   = (ushort_t*)(ws + WS_WL);
    ushort_t* pTs  = (ushort_t*)(ws + WS_PTS);
    float* add  = ws + WS_ADD;

    im2col_bf16_k<<<(CROWS * DMODEL / 4 + 255) / 256, 256, 0, stream>>>(x, tb);
    cvt_w_k<<<(DMODEL * DMODEL / 4 + 255) / 256, 256, 0, stream>>>(conv1_w, wl, DMODEL * DMODEL);
    gemm_mfma_k<<<dim3((CROWS + 127) / 128, DMODEL / 128), 256, 0, stream>>>(
        tb, wl, nullptr, ctmp, nullptr, CROWS, DMODEL, DMODEL, 0);
    embed_k<<<(ROWS * DMODEL + 255) / 256, 256, 0, stream>>>(ctmp, cls, pos, h);
    ln768_k<<<ROWS, 256, 0, stream>>>(h, h, ln_pre_w, ln_pre_b);
    gauss_k<<<(NTOK * NTOK + 255) / 256, 256, 0, stream>>>(add);
    cvt_pT_k<<<(DOUT * DMODEL + 255) / 256, 256, 0, stream>>>(proj, pTs);

    const int GY = (ROWS + 127) / 128;  // 50
    for (int l = 0; l < NLAYER; ++l) {
        cvt_layer_k<<<(int)(WTOT / 4 / 256), 256, 0, stream>>>(
            in_proj_w + (size_t)l * DQKV * DMODEL, out_proj_w + (size_t)l * DMODEL * DMODEL,
            fc_w + (size_t)l * DFF * DMODEL, cproj_w + (size_t)l * DMODEL * DFF, wl);
        ln768_bf16_k<<<ROWS, 256, 0, stream>>>(h, tb, ln1_w + l * DMODEL, ln1_b + l * DMODEL);
        gemm_mfma_k<<<dim3(GY, DQKV / 128), 256, 0, stream>>>(
            tb, wl + WOFF_IN, in_proj_b + (size_t)l * DQKV, nullptr, qkvb, ROWS, DQKV, DMODEL, 4);
        bool nac = (l == NLAYER - 1);
        attn_fused_k<<<NBH, 512, 0, stream>>>(qkvb, tb, nac ? add : nullptr, nac ? DMODEL : 0);
        gemm_mfma_k<<<dim3(GY, DMODEL / 128, 2), 256, 0, stream>>>(
            tb, wl + WOFF_OUT, out_proj_b + (size_t)l * DMODEL, h, nullptr, ROWS, DMODEL, DMODEL, 3);
        ln768_bf16_k<<<ROWS, 256, 0, stream>>>(h, tb, ln2_w + l * DMODEL, ln2_b + l * DMODEL);
        gemm_mfma_k<<<dim3(GY, DFF / 128), 256, 0, stream>>>(
            tb, wl + WOFF_FC, fc_b + (size_t)l * DFF, nullptr, gb, ROWS, DFF, DMODEL, 1);
        gemm_mfma_k<<<dim3(GY, DMODEL / 128, 2), 256, 0, stream>>>(
            gb, wl + WOFF_CP, cproj_b + (size_t)l * DMODEL, h, nullptr, ROWS, DMODEL, DFF, 3);
    }

    ln768_bf16_k<<<ROWS, 256, 0, stream>>>(h, tb, ln_post_w, ln_post_b);
    gemm_mfma_k<<<dim3(GY, DOUT / 128), 256, 0, stream>>>(
        tb, pTs, nullptr, out, nullptr, ROWS, DOUT, DMODEL, 0);
}

// Round 9
// 3266.863 us; speedup vs baseline: 1.1482x; 1.0789x over previous
//
#include <hip/hip_runtime.h>
#include <hip/hip_bf16.h>
#include <math.h>

// ---------------- problem constants ----------------
#define BATCH 32
#define NTOK  197
#define NPATCH 196
#define DMODEL 768
#define NLAYER 12
#define NHEAD 12
#define HDIM  64
#define ROWS  (BATCH*NTOK)     // 6304
#define CROWS (BATCH*NPATCH)   // 6272
#define DFF   3072
#define DQKV  2304
#define DOUT  512
#define NBH   (BATCH*NHEAD)

// per-layer weight slab offsets (bf16 elems)
#define WOFF_IN   ((size_t)0)
#define WOFF_OUT  ((size_t)(DQKV*DMODEL))
#define WOFF_FC   (WOFF_OUT + (size_t)(DMODEL*DMODEL))
#define WOFF_CP   (WOFF_FC + (size_t)(DFF*DMODEL))
#define WTOT      (WOFF_CP + (size_t)(DMODEL*DFF))

// workspace layout (float units)
#define WS_H    ((size_t)0)
#define WS_QKVB (WS_H + (size_t)ROWS*DMODEL)
#define WS_GB   (WS_QKVB + (size_t)ROWS*DQKV/2)
#define WS_TB   (WS_GB + (size_t)ROWS*DFF/2)
#define WS_WL   (WS_TB + (size_t)ROWS*DMODEL/2)
#define WS_PTS  (WS_WL + WTOT/2)
#define WS_ADD  (WS_PTS + (size_t)DOUT*DMODEL/2)

typedef unsigned short ushort_t;
typedef __attribute__((ext_vector_type(8))) short bf16x8;
typedef __attribute__((ext_vector_type(4))) float f32x4;

__device__ inline ushort_t bf16rn(float x) {
    uint32_t u = __builtin_bit_cast(uint32_t, x);
    uint32_t r = (u + 0x7FFFu + ((u >> 16) & 1u)) >> 16;
    return (ushort_t)r;
}

#define GLL(src, dst) __builtin_amdgcn_global_load_lds( \
    (const __attribute__((address_space(1))) void*)(src), \
    (__attribute__((address_space(3))) void*)(dst), 16, 0, 0)

// ---------------- small kernels ----------------

__global__ void im2col_bf16_k(const float* __restrict__ x, ushort_t* __restrict__ out) {
    int idx = blockIdx.x * 256 + threadIdx.x;
    if (idx >= CROWS * DMODEL / 4) return;
    int r  = idx / (DMODEL / 4);
    int k4 = (idx - r * (DMODEL / 4)) * 4;
    int b = r / NPATCH, p = r - b * NPATCH;
    int py = p / 14, px = p - py * 14;
    int c = k4 >> 8, rem = k4 & 255, i = rem >> 4, j = rem & 15;
    const float* xp = x + (((size_t)(b * 3 + c) * 224) + py * 16 + i) * 224 + px * 16 + j;
    float4 v = *(const float4*)xp;
    ushort4 hv = {bf16rn(v.x), bf16rn(v.y), bf16rn(v.z), bf16rn(v.w)};
    *(ushort4*)(out + (size_t)r * DMODEL + k4) = hv;
}

__global__ void cvt_w_k(const float* __restrict__ W, ushort_t* __restrict__ out, int NK) {
    int idx = (blockIdx.x * 256 + threadIdx.x) * 4;
    if (idx >= NK) return;
    float4 v = *(const float4*)(W + idx);
    ushort4 hv = {bf16rn(v.x), bf16rn(v.y), bf16rn(v.z), bf16rn(v.w)};
    *(ushort4*)(out + idx) = hv;
}

__global__ void cvt_layer_k(const float* __restrict__ inW, const float* __restrict__ outW,
                            const float* __restrict__ fcW, const float* __restrict__ cpW,
                            ushort_t* __restrict__ wl) {
    size_t idx = ((size_t)blockIdx.x * 256 + threadIdx.x) * 4;
    if (idx >= WTOT) return;
    const float* src; size_t off;
    if (idx < WOFF_OUT)      { src = inW;  off = idx; }
    else if (idx < WOFF_FC)  { src = outW; off = idx - WOFF_OUT; }
    else if (idx < WOFF_CP)  { src = fcW;  off = idx - WOFF_FC; }
    else                     { src = cpW;  off = idx - WOFF_CP; }
    float4 v = *(const float4*)(src + off);
    ushort4 hv = {bf16rn(v.x), bf16rn(v.y), bf16rn(v.z), bf16rn(v.w)};
    *(ushort4*)(wl + idx) = hv;
}

__global__ void cvt_pT_k(const float* __restrict__ proj, ushort_t* __restrict__ out) {
    int idx = blockIdx.x * 256 + threadIdx.x;
    if (idx >= DOUT * DMODEL) return;
    int n = idx / DMODEL, k = idx - n * DMODEL;
    out[(size_t)n * DMODEL + k] = bf16rn(proj[(size_t)k * DOUT + n]);
}

__global__ void embed_k(const float* __restrict__ conv, const float* __restrict__ cls,
                        const float* __restrict__ pos, float* __restrict__ h) {
    int idx = blockIdx.x * 256 + threadIdx.x;
    if (idx >= ROWS * DMODEL) return;
    int r = idx / DMODEL, d = idx - r * DMODEL;
    int b = r / NTOK, tok = r - b * NTOK;
    float v = (tok == 0) ? cls[d] : conv[((size_t)(b * NPATCH + tok - 1)) * DMODEL + d];
    h[idx] = v + pos[(size_t)tok * DMODEL + d];
}

__global__ void gauss_k(float* __restrict__ add) {
    int idx = blockIdx.x * 256 + threadIdx.x;
    if (idx >= NTOK * NTOK) return;
    int i = idx / NTOK, j = idx - i * NTOK;
    float v = 0.f;
    if (i > 0 && j > 0) {
        int p = i - 1, q = j - 1;
        int di = q / 14 - p / 14;
        int dj = q % 14 - p % 14;
        v = expf(-(float)(di * di + dj * dj) * 0.02f);
    }
    add[idx] = v;
}

__global__ __launch_bounds__(256) void ln768_k(const float* __restrict__ in, float* __restrict__ out,
                                               const float* __restrict__ w, const float* __restrict__ b) {
    int row = blockIdx.x, tid = threadIdx.x;
    const float* x = in + (size_t)row * DMODEL;
    float v0 = x[tid], v1 = x[tid + 256], v2 = x[tid + 512];
    float s = v0 + v1 + v2;
    float s2 = v0 * v0 + v1 * v1 + v2 * v2;
    for (int o = 32; o > 0; o >>= 1) { s += __shfl_down(s, o); s2 += __shfl_down(s2, o); }
    __shared__ float red[8];
    int wid = tid >> 6;
    if ((tid & 63) == 0) { red[wid] = s; red[4 + wid] = s2; }
    __syncthreads();
    s  = red[0] + red[1] + red[2] + red[3];
    s2 = red[4] + red[5] + red[6] + red[7];
    float mean = s * (1.0f / 768.0f);
    float var  = s2 * (1.0f / 768.0f) - mean * mean;
    float rinv = rsqrtf(var + 1e-5f);
    float* o_ = out + (size_t)row * DMODEL;
    o_[tid]       = (v0 - mean) * rinv * w[tid]       + b[tid];
    o_[tid + 256] = (v1 - mean) * rinv * w[tid + 256] + b[tid + 256];
    o_[tid + 512] = (v2 - mean) * rinv * w[tid + 512] + b[tid + 512];
}

__global__ __launch_bounds__(256) void ln768_bf16_k(const float* __restrict__ in, ushort_t* __restrict__ out,
                                                    const float* __restrict__ w, const float* __restrict__ b) {
    int row = blockIdx.x, tid = threadIdx.x;
    const float* x = in + (size_t)row * DMODEL;
    float v0 = x[tid], v1 = x[tid + 256], v2 = x[tid + 512];
    float s = v0 + v1 + v2;
    float s2 = v0 * v0 + v1 * v1 + v2 * v2;
    for (int o = 32; o > 0; o >>= 1) { s += __shfl_down(s, o); s2 += __shfl_down(s2, o); }
    __shared__ float red[8];
    int wid = tid >> 6;
    if ((tid & 63) == 0) { red[wid] = s; red[4 + wid] = s2; }
    __syncthreads();
    s  = red[0] + red[1] + red[2] + red[3];
    s2 = red[4] + red[5] + red[6] + red[7];
    float mean = s * (1.0f / 768.0f);
    float var  = s2 * (1.0f / 768.0f) - mean * mean;
    float rinv = rsqrtf(var + 1e-5f);
    ushort_t* o_ = out + (size_t)row * DMODEL;
    o_[tid]       = bf16rn((v0 - mean) * rinv * w[tid]       + b[tid]);
    o_[tid + 256] = bf16rn((v1 - mean) * rinv * w[tid + 256] + b[tid + 256]);
    o_[tid + 512] = bf16rn((v2 - mean) * rinv * w[tid + 512] + b[tid + 512]);
}

// ---------------- single-barrier, depth-2 MFMA GEMM:  C[M,N] (+)= A[M,K] @ W[N,K]^T ----------------
// 3 LDS buffers; per iter: vmcnt(4) -> barrier -> ds_read buf[t%3] -> STAGE(t+2) -> 16 MFMA.
// Safety: only same-epoch writer/reader pair is STAGE(t+2) vs reads buf[t%3]; 2 != 0 mod 3.
// mode 0: C = r + bias (f32)
// mode 1: OS = bf16(quick_gelu(r + bias))
// mode 3: atomicAdd(C, r (+bias if blockIdx.z==0))
// mode 4: OS = bf16(r + bias)
__global__ __launch_bounds__(256) void gemm_mfma_k(
    const ushort_t* __restrict__ A, const ushort_t* __restrict__ W,
    const float* __restrict__ bias, float* __restrict__ C, ushort_t* __restrict__ OS,
    int M, int N, int K, int mode)
{
    __shared__ ushort_t As[3][128][32];
    __shared__ ushort_t Bs[3][128][32];
    int tid = threadIdx.x;
    int lane = tid & 63;
    int wave = tid >> 6;
    int wm = wave >> 1, wn = wave & 1;
    int m0 = blockIdx.x * 128, n0 = blockIdx.y * 128;

    int klen = K / gridDim.z;
    int kbeg = blockIdx.z * klen;
    int nt = klen / 32;

    f32x4 acc[4][4];
    #pragma unroll
    for (int i = 0; i < 4; ++i)
        #pragma unroll
        for (int j = 0; j < 4; ++j)
            acc[i][j] = (f32x4){0.f, 0.f, 0.f, 0.f};

    int srow = tid >> 2;
    int skq  = (((tid & 3) ^ ((tid >> 3) & 3)) * 8);      // pre-swizzled source slot
    int ar0 = m0 + srow;      if (ar0 > M - 1) ar0 = M - 1;
    int ar1 = m0 + srow + 64; if (ar1 > M - 1) ar1 = M - 1;
    const ushort_t* Ap0 = A + (size_t)ar0 * K + kbeg + skq;
    const ushort_t* Ap1 = A + (size_t)ar1 * K + kbeg + skq;
    const ushort_t* Wp0 = W + (size_t)(n0 + srow) * K + kbeg + skq;
    const ushort_t* Wp1 = W + (size_t)(n0 + srow + 64) * K + kbeg + skq;
    char* ldsA = (char*)As + tid * 16;
    char* ldsB = (char*)Bs + tid * 16;

    int fr = lane & 15, fq = lane >> 4;
    int rsl = (fq ^ ((fr >> 1) & 3)) * 8;                 // swizzled read slot

    #define STAGE(buf_, ko_) do {                         \
        GLL(Ap0 + (ko_), ldsA + (buf_) * 8192);           \
        GLL(Ap1 + (ko_), ldsA + (buf_) * 8192 + 4096);    \
        GLL(Wp0 + (ko_), ldsB + (buf_) * 8192);           \
        GLL(Wp1 + (ko_), ldsB + (buf_) * 8192 + 4096);    \
    } while (0)

    STAGE(0, 0);
    if (nt > 1) STAGE(1, 32);

    for (int t = 0; t < nt; ++t) {
        int cur = t % 3;
        if (t + 1 < nt) {
            asm volatile("s_waitcnt vmcnt(4)" ::: "memory");
        } else {
            asm volatile("s_waitcnt vmcnt(0)" ::: "memory");
        }
        __builtin_amdgcn_s_barrier();
        bf16x8 a[4], b[4];
        #pragma unroll
        for (int fm = 0; fm < 4; ++fm)
            a[fm] = *(const bf16x8*)&As[cur][wm * 64 + fm * 16 + fr][rsl];
        #pragma unroll
        for (int fn = 0; fn < 4; ++fn)
            b[fn] = *(const bf16x8*)&Bs[cur][wn * 64 + fn * 16 + fr][rsl];
        if (t + 2 < nt) STAGE((t + 2) % 3, (size_t)(t + 2) * 32);
        #pragma unroll
        for (int fm = 0; fm < 4; ++fm)
            #pragma unroll
            for (int fn = 0; fn < 4; ++fn)
                acc[fm][fn] = __builtin_amdgcn_mfma_f32_16x16x32_bf16(a[fm], b[fn], acc[fm][fn], 0, 0, 0);
    }
    #undef STAGE

    // epilogue: D col = lane&15 (fr), row = fq*4 + j
    #pragma unroll
    for (int fn = 0; fn < 4; ++fn) {
        int ccol = n0 + wn * 64 + fn * 16 + fr;
        float bv = bias ? bias[ccol] : 0.f;
        if (mode == 3 && blockIdx.z != 0) bv = 0.f;
        #pragma unroll
        for (int fm = 0; fm < 4; ++fm) {
            int crow0 = m0 + wm * 64 + fm * 16 + fq * 4;
            #pragma unroll
            for (int j = 0; j < 4; ++j) {
                int row = crow0 + j;
                if (row < M) {
                    float v = acc[fm][fn][j] + bv;
                    if (mode == 0) {
                        C[(size_t)row * N + ccol] = v;
                    } else if (mode == 3) {
                        atomicAdd(&C[(size_t)row * N + ccol], v);
                    } else if (mode == 4) {
                        OS[(size_t)row * N + ccol] = bf16rn(v);
                    } else {
                        v = v / (1.0f + expf(-1.702f * v));
                        OS[(size_t)row * N + ccol] = bf16rn(v);
                    }
                }
            }
        }
    }
}

// ---------------- fused MFMA flash attention, swapped-QK^T, 8 waves, q-split ----------------
// grid (NBH, 2): blockIdx.y selects q-tile range; each wave handles at most one q-tile.
__global__ __launch_bounds__(512, 4) void attn_fused_k(
    const ushort_t* __restrict__ qkvb, ushort_t* __restrict__ out,
    const float* __restrict__ addition, int qoff)
{
    __shared__ ushort_t Ks[208][72];
    __shared__ ushort_t Vt[64][232];
    __shared__ ushort_t Pb[8][2][16][40];
    int tid = threadIdx.x;
    int bh = blockIdx.x;
    int b = bh / NHEAD, hh = bh - b * NHEAD;
    const ushort_t* base = qkvb + (size_t)b * NTOK * DQKV + hh * HDIM;

    int lane = tid & 63, wave = tid >> 6;
    int fr = lane & 15, fq = lane >> 4;
    int qt = blockIdx.y * 8 + wave;       // 0..15, valid if < 13

    // prefetch Q fragments (hides under staging)
    bf16x8 qf0, qf1;
    if (qt < 13) {
        int qrow = qt * 16 + fr; if (qrow > NTOK - 1) qrow = NTOK - 1;
        const ushort_t* qp = base + (size_t)qrow * DQKV + qoff + fq * 8;
        qf0 = *(const bf16x8*)qp;
        qf1 = *(const bf16x8*)(qp + 32);
    }

    // stage K [208][72] and V^T [64][232]
    {
        int tt = tid >> 4, dq = tid & 15;
        #pragma unroll
        for (int pass = 0; pass < 7; ++pass) {
            int t = pass * 32 + tt;
            if (t < 208) {
                ushort4 kv = {0, 0, 0, 0}, vv = {0, 0, 0, 0};
                if (t < NTOK) {
                    kv = *(const ushort4*)(base + (size_t)t * DQKV + DMODEL + dq * 4);
                    vv = *(const ushort4*)(base + (size_t)t * DQKV + 2 * DMODEL + dq * 4);
                }
                *(ushort4*)&Ks[t][dq * 4] = kv;
                Vt[dq * 4 + 0][t] = vv.x;
                Vt[dq * 4 + 1][t] = vv.y;
                Vt[dq * 4 + 2][t] = vv.z;
                Vt[dq * 4 + 3][t] = vv.w;
            }
        }
        for (int z = tid; z < 64 * 24; z += 512) Vt[z / 24][208 + z % 24] = 0;
    }
    __syncthreads();

    if (qt < 13) {
        int i0 = qt * 16;
        int irow = i0 + fr; if (irow > NTOK - 1) irow = NTOK - 1;

        // S^T = K Q^T : lane holds S[i=i0+fr][j = jt*16 + fq*4 + jj]
        f32x4 s[13];
        #pragma unroll
        for (int jt = 0; jt < 13; ++jt) {
            bf16x8 k0 = *(const bf16x8*)&Ks[jt * 16 + fr][fq * 8];
            bf16x8 k1 = *(const bf16x8*)&Ks[jt * 16 + fr][32 + fq * 8];
            f32x4 a = {0.f, 0.f, 0.f, 0.f};
            a = __builtin_amdgcn_mfma_f32_16x16x32_bf16(k0, qf0, a, 0, 0, 0);
            a = __builtin_amdgcn_mfma_f32_16x16x32_bf16(k1, qf1, a, 0, 0, 0);
            s[jt] = a;
        }

        float mx = -1e30f;
        #pragma unroll
        for (int jt = 0; jt < 13; ++jt) {
            int jb = jt * 16 + fq * 4;
            #pragma unroll
            for (int jj = 0; jj < 4; ++jj) {
                int j = jb + jj;
                float v = s[jt][jj] * 0.125f;
                if (addition) v += addition[irow * NTOK + (j < NTOK ? j : NTOK - 1)];
                if (j >= NTOK) v = -1e30f;
                s[jt][jj] = v;
                mx = fmaxf(mx, v);
            }
        }
        mx = fmaxf(mx, __shfl_xor(mx, 16));
        mx = fmaxf(mx, __shfl_xor(mx, 32));
        float sum = 0.f;
        #pragma unroll
        for (int jt = 0; jt < 13; ++jt)
            #pragma unroll
            for (int jj = 0; jj < 4; ++jj) {
                float e = __expf(s[jt][jj] - mx);
                s[jt][jj] = e;
                sum += e;
            }
        sum += __shfl_xor(sum, 16);
        sum += __shfl_xor(sum, 32);
        float inv = 1.0f / sum;

        f32x4 o4[4];
        #pragma unroll
        for (int dt = 0; dt < 4; ++dt) o4[dt] = (f32x4){0.f, 0.f, 0.f, 0.f};

        #define WRITE_P(st_, buf_) do {                                              \
            int jA = 2 * (st_), jB = jA + 1;                                         \
            ushort4 wa = {bf16rn(s[jA][0] * inv), bf16rn(s[jA][1] * inv),            \
                          bf16rn(s[jA][2] * inv), bf16rn(s[jA][3] * inv)};           \
            ushort4 wb = {0, 0, 0, 0};                                               \
            if (jB < 13) wb = (ushort4){bf16rn(s[jB][0] * inv), bf16rn(s[jB][1] * inv), \
                                        bf16rn(s[jB][2] * inv), bf16rn(s[jB][3] * inv)}; \
            *(ushort4*)&Pb[wave][buf_][fr][fq * 4] = wa;                             \
            *(ushort4*)&Pb[wave][buf_][fr][16 + fq * 4] = wb;                        \
        } while (0)

        WRITE_P(0, 0);
        for (int st = 0; st < 7; ++st) {
            asm volatile("s_waitcnt lgkmcnt(0)" ::: "memory");
            bf16x8 pa = *(const bf16x8*)&Pb[wave][st & 1][fr][fq * 8];
            bf16x8 vf0 = *(const bf16x8*)&Vt[0 * 16 + fr][st * 32 + fq * 8];
            bf16x8 vf1 = *(const bf16x8*)&Vt[1 * 16 + fr][st * 32 + fq * 8];
            bf16x8 vf2 = *(const bf16x8*)&Vt[2 * 16 + fr][st * 32 + fq * 8];
            bf16x8 vf3 = *(const bf16x8*)&Vt[3 * 16 + fr][st * 32 + fq * 8];
            if (st < 6) WRITE_P(st + 1, (st + 1) & 1);
            o4[0] = __builtin_amdgcn_mfma_f32_16x16x32_bf16(pa, vf0, o4[0], 0, 0, 0);
            o4[1] = __builtin_amdgcn_mfma_f32_16x16x32_bf16(pa, vf1, o4[1], 0, 0, 0);
            o4[2] = __builtin_amdgcn_mfma_f32_16x16x32_bf16(pa, vf2, o4[2], 0, 0, 0);
            o4[3] = __builtin_amdgcn_mfma_f32_16x16x32_bf16(pa, vf3, o4[3], 0, 0, 0);
        }
        #undef WRITE_P

        #pragma unroll
        for (int jj = 0; jj < 4; ++jj) {
            int ir = i0 + fq * 4 + jj;
            if (ir < NTOK) {
                ushort_t* op = out + ((size_t)(b * NTOK + ir)) * DMODEL + hh * HDIM + fr;
                #pragma unroll
                for (int dt = 0; dt < 4; ++dt)
                    op[dt * 16] = bf16rn(o4[dt][jj]);
            }
        }
    }
}

// ---------------- launch ----------------
extern "C" void kernel_launch(void* const* d_in, const int* in_sizes, int n_in,
                              void* d_out, int out_size, void* d_ws, size_t ws_size,
                              hipStream_t stream) {
    const float* x        = (const float*)d_in[0];
    const float* conv1_w  = (const float*)d_in[1];
    const float* cls      = (const float*)d_in[2];
    const float* pos      = (const float*)d_in[3];
    const float* ln_pre_w = (const float*)d_in[4];
    const float* ln_pre_b = (const float*)d_in[5];
    const float* in_proj_w  = (const float*)d_in[6];
    const float* in_proj_b  = (const float*)d_in[7];
    const float* out_proj_w = (const float*)d_in[8];
    const float* out_proj_b = (const float*)d_in[9];
    const float* ln1_w = (const float*)d_in[10];
    const float* ln1_b = (const float*)d_in[11];
    const float* ln2_w = (const float*)d_in[12];
    const float* ln2_b = (const float*)d_in[13];
    const float* fc_w  = (const float*)d_in[14];
    const float* fc_b  = (const float*)d_in[15];
    const float* cproj_w = (const float*)d_in[16];
    const float* cproj_b = (const float*)d_in[17];
    const float* ln_post_w = (const float*)d_in[18];
    const float* ln_post_b = (const float*)d_in[19];
    const float* proj = (const float*)d_in[20];
    float* out = (float*)d_out;

    float* ws   = (float*)d_ws;
    float* h    = ws + WS_H;
    float* ctmp = ws + WS_QKVB;
    ushort_t* qkvb = (ushort_t*)(ws + WS_QKVB);
    ushort_t* gb   = (ushort_t*)(ws + WS_GB);
    ushort_t* tb   = (ushort_t*)(ws + WS_TB);
    ushort_t* wl   = (ushort_t*)(ws + WS_WL);
    ushort_t* pTs  = (ushort_t*)(ws + WS_PTS);
    float* add  = ws + WS_ADD;

    im2col_bf16_k<<<(CROWS * DMODEL / 4 + 255) / 256, 256, 0, stream>>>(x, tb);
    cvt_w_k<<<(DMODEL * DMODEL / 4 + 255) / 256, 256, 0, stream>>>(conv1_w, wl, DMODEL * DMODEL);
    gemm_mfma_k<<<dim3((CROWS + 127) / 128, DMODEL / 128), 256, 0, stream>>>(
        tb, wl, nullptr, ctmp, nullptr, CROWS, DMODEL, DMODEL, 0);
    embed_k<<<(ROWS * DMODEL + 255) / 256, 256, 0, stream>>>(ctmp, cls, pos, h);
    ln768_k<<<ROWS, 256, 0, stream>>>(h, h, ln_pre_w, ln_pre_b);
    gauss_k<<<(NTOK * NTOK + 255) / 256, 256, 0, stream>>>(add);
    cvt_pT_k<<<(DOUT * DMODEL + 255) / 256, 256, 0, stream>>>(proj, pTs);

    const int GY = (ROWS + 127) / 128;  // 50
    for (int l = 0; l < NLAYER; ++l) {
        cvt_layer_k<<<(int)(WTOT / 4 / 256), 256, 0, stream>>>(
            in_proj_w + (size_t)l * DQKV * DMODEL, out_proj_w + (size_t)l * DMODEL * DMODEL,
            fc_w + (size_t)l * DFF * DMODEL, cproj_w + (size_t)l * DMODEL * DFF, wl);
        ln768_bf16_k<<<ROWS, 256, 0, stream>>>(h, tb, ln1_w + l * DMODEL, ln1_b + l * DMODEL);
        gemm_mfma_k<<<dim3(GY, DQKV / 128), 256, 0, stream>>>(
            tb, wl + WOFF_IN, in_proj_b + (size_t)l * DQKV, nullptr, qkvb, ROWS, DQKV, DMODEL, 4);
        bool nac = (l == NLAYER - 1);
        attn_fused_k<<<dim3(NBH, 2), 512, 0, stream>>>(qkvb, tb, nac ? add : nullptr, nac ? DMODEL : 0);
        gemm_mfma_k<<<dim3(GY, DMODEL / 128, 2), 256, 0, stream>>>(
            tb, wl + WOFF_OUT, out_proj_b + (size_t)l * DMODEL, h, nullptr, ROWS, DMODEL, DMODEL, 3);
        ln768_bf16_k<<<ROWS, 256, 0, stream>>>(h, tb, ln2_w + l * DMODEL, ln2_b + l * DMODEL);
        gemm_mfma_k<<<dim3(GY, DFF / 128), 256, 0, stream>>>(
            tb, wl + WOFF_FC, fc_b + (size_t)l * DFF, nullptr, gb, ROWS, DFF, DMODEL, 1);
        gemm_mfma_k<<<dim3(GY, DMODEL / 128, 2), 256, 0, stream>>>(
            gb, wl + WOFF_CP, cproj_b + (size_t)l * DMODEL, h, nullptr, ROWS, DMODEL, DFF, 3);
    }

    ln768_bf16_k<<<ROWS, 256, 0, stream>>>(h, tb, ln_post_w, ln_post_b);
    gemm_mfma_k<<<dim3(GY, DOUT / 128), 256, 0, stream>>>(
        tb, pTs, nullptr, out, nullptr, ROWS, DOUT, DMODEL, 0);
}